// Round 4
// baseline (446.731 us; speedup 1.0000x reference)
//
#include <hip/hip_runtime.h>

#define N 8192
#define D 128
#define ALPHA 0.2f
#define RCAP 256   // per-row nnz capacity; E[nnz]=83, sd=9

// ---------------------------------------------------------------------------
// Kernel 1: H = X @ W^T + b ; s = H @ a_s ; r = H @ a_r   (unchanged)
// ---------------------------------------------------------------------------
__global__ __launch_bounds__(256) void linear_kernel(
    const float* __restrict__ X, const float* __restrict__ W,
    const float* __restrict__ b, const float* __restrict__ a_s,
    const float* __restrict__ a_r,
    float* __restrict__ H, float* __restrict__ sv, float* __restrict__ rv)
{
    __shared__ float Xs[128 * 36];
    __shared__ float Ws[64 * 132];

    const int tid = threadIdx.x;
    const int i0  = blockIdx.x * 32;

    for (int idx = tid; idx < 32 * 128; idx += 256) {
        const int row = idx >> 7, k = idx & 127;
        Xs[k * 36 + row] = X[(i0 + row) * D + k];
    }

    float acc[4][4] = {};
    const int ty = tid >> 5, tx = tid & 31;
    const int rbase = ty * 4, cbase = tx * 4;

    for (int kb = 0; kb < 2; ++kb) {
        __syncthreads();
        for (int idx = tid; idx < 64 * 128; idx += 256) {
            const int o = idx >> 6, kk = idx & 63;
            Ws[kk * 132 + o] = W[o * D + kb * 64 + kk];
        }
        __syncthreads();
        #pragma unroll
        for (int kk = 0; kk < 64; ++kk) {
            const float4 xv = *(const float4*)&Xs[(kb * 64 + kk) * 36 + rbase];
            const float4 wv = *(const float4*)&Ws[kk * 132 + cbase];
            const float xr[4] = {xv.x, xv.y, xv.z, xv.w};
            const float wc[4] = {wv.x, wv.y, wv.z, wv.w};
            #pragma unroll
            for (int r = 0; r < 4; ++r)
                #pragma unroll
                for (int c = 0; c < 4; ++c)
                    acc[r][c] += xr[r] * wc[c];
        }
    }

    const float4 bv  = *(const float4*)&b[cbase];
    const float4 asv = *(const float4*)&a_s[cbase];
    const float4 arv = *(const float4*)&a_r[cbase];
    #pragma unroll
    for (int r = 0; r < 4; ++r) {
        float4 h;
        h.x = acc[r][0] + bv.x;
        h.y = acc[r][1] + bv.y;
        h.z = acc[r][2] + bv.z;
        h.w = acc[r][3] + bv.w;
        *(float4*)&H[(size_t)(i0 + rbase + r) * D + cbase] = h;
        float ps = h.x * asv.x + h.y * asv.y + h.z * asv.z + h.w * asv.w;
        float pr = h.x * arv.x + h.y * arv.y + h.z * arv.z + h.w * arv.w;
        #pragma unroll
        for (int off = 16; off > 0; off >>= 1) {
            ps += __shfl_xor(ps, off);
            pr += __shfl_xor(pr, off);
        }
        if (tx == 0) {
            sv[i0 + rbase + r] = ps;
            rv[i0 + rbase + r] = pr;
        }
    }
}

// ---------------------------------------------------------------------------
// Kernel 2: fused scan + softmax + gather. ONE WAVE PER ROW.
// Phase 1: 8 iters x 4KB (4 float4/lane), double-buffered prefetch;
//          per-lane 16-bit nonzero mask + ONE wave prefix-scan per iter
//          (replaces 16 ballots); lanes scatter their own cols to LDS.
//          List order != column order — softmax/sum are permutation-invariant.
// Phase 2: scores + shuffle softmax. Phase 3: coalesced H-gather.
// ---------------------------------------------------------------------------
__global__ __launch_bounds__(256, 6) void attn_fused(
    const float* __restrict__ A, const float* __restrict__ H,
    const float* __restrict__ sv, const float* __restrict__ rv,
    float* __restrict__ out)
{
    __shared__ float2 s_l[4][RCAP];   // .x = weight, .y = column index (bits)

    const int wave = threadIdx.x >> 6;
    const int lane = threadIdx.x & 63;
    const int i    = blockIdx.x * 4 + wave;

    const float4* __restrict__ Arow = (const float4*)(A + (size_t)i * N);

    // ---- phase 1: scan row, compact nonzero columns into LDS ----
    float4 buf[2][4];
    #pragma unroll
    for (int q = 0; q < 4; ++q) buf[0][q] = Arow[q * 64 + lane];

    int cnt = 0;
    #pragma unroll 1
    for (int it = 0; it < 8; ++it) {
        const int cb = it & 1;
        if (it < 7) {
            #pragma unroll
            for (int q = 0; q < 4; ++q)
                buf[cb ^ 1][q] = Arow[(it + 1) * 256 + q * 64 + lane];
        }
        // per-lane 16-bit nonzero mask (pure VALU, no cross-lane ops)
        unsigned m = 0;
        #pragma unroll
        for (int q = 0; q < 4; ++q) {
            const float4 a = buf[cb][q];
            m |= (a.x != 0.0f ? 1u : 0u) << (q * 4 + 0);
            m |= (a.y != 0.0f ? 1u : 0u) << (q * 4 + 1);
            m |= (a.z != 0.0f ? 1u : 0u) << (q * 4 + 2);
            m |= (a.w != 0.0f ? 1u : 0u) << (q * 4 + 3);
        }
        const int c = __popc(m);
        // wave inclusive scan of c
        int scan = c;
        #pragma unroll
        for (int off = 1; off < 64; off <<= 1) {
            const int t = __shfl_up(scan, off);
            if (lane >= off) scan += t;
        }
        int base = cnt + scan - c;            // this lane's exclusive offset
        cnt += __shfl(scan, 63);              // wave-uniform total
        // scatter this lane's columns
        while (m) {
            const int k = __ffs(m) - 1;
            m &= m - 1;
            const int q = k >> 2, e = k & 3;
            if (base < RCAP)
                s_l[wave][base].y = __int_as_float(it * 1024 + q * 256 + lane * 4 + e);
            ++base;
        }
    }
    cnt = (cnt < RCAP) ? cnt : RCAP;

    // ---- phase 2: scores + softmax (<=4 entries per lane) ----
    const float si = sv[i];
    float zv[4];
    #pragma unroll
    for (int k = 0; k < 4; ++k) {
        const int p = lane + 64 * k;
        const bool act = (p < cnt);
        const int j = act ? __float_as_int(s_l[wave][p].y) : 0;
        float z = si + rv[j];
        z = (z > 0.0f) ? z : ALPHA * z;
        zv[k] = act ? z : -3.0e38f;
    }
    float lm = fmaxf(fmaxf(zv[0], zv[1]), fmaxf(zv[2], zv[3]));
    #pragma unroll
    for (int off = 32; off > 0; off >>= 1) lm = fmaxf(lm, __shfl_xor(lm, off));

    float sl = 0.0f;
    float wv4[4];
    #pragma unroll
    for (int k = 0; k < 4; ++k) {
        const int p = lane + 64 * k;
        const float w = (p < cnt) ? __expf(zv[k] - lm) : 0.0f;
        wv4[k] = w;
        sl += w;
    }
    #pragma unroll
    for (int off = 32; off > 0; off >>= 1) sl += __shfl_xor(sl, off);
    const float inv = 1.0f / sl;

    #pragma unroll
    for (int k = 0; k < 4; ++k) {
        const int p = lane + 64 * k;
        if (p < cnt) s_l[wave][p].x = wv4[k] * inv;
    }

    // ---- phase 3: weighted gather; each lane owns features 2*lane, 2*lane+1 ----
    float2 acc = make_float2(0.0f, 0.0f);
    const float* __restrict__ Hl = H + 2 * lane;
    #pragma unroll 4
    for (int p = 0; p < cnt; ++p) {
        const float2 wj = s_l[wave][p];               // one b64 broadcast read
        const int   j  = __float_as_int(wj.y);
        const float2 h = *(const float2*)&Hl[(size_t)j * D];
        acc.x += wj.x * h.x;
        acc.y += wj.x * h.y;
    }
    *(float2*)&out[(size_t)i * D + 2 * lane] = acc;
}

extern "C" void kernel_launch(void* const* d_in, const int* in_sizes, int n_in,
                              void* d_out, int out_size, void* d_ws, size_t ws_size,
                              hipStream_t stream) {
    const float* X   = (const float*)d_in[0];
    const float* A   = (const float*)d_in[1];
    const float* W   = (const float*)d_in[2];
    const float* b   = (const float*)d_in[3];
    const float* a_s = (const float*)d_in[4];
    const float* a_r = (const float*)d_in[5];
    float* out = (float*)d_out;

    float* H  = (float*)d_ws;               // N*D floats = 4 MB
    float* sv = H + (size_t)N * D;          // N floats
    float* rv = sv + N;                     // N floats

    linear_kernel<<<256, 256, 0, stream>>>(X, W, b, a_s, a_r, H, sv, rv);
    attn_fused<<<N / 4, 256, 0, stream>>>(A, H, sv, rv, out);
}

// Round 5
// 388.753 us; speedup vs baseline: 1.1491x; 1.1491x over previous
//
#include <hip/hip_runtime.h>

#define N 8192
#define D 128
#define ALPHA 0.2f
#define RCAP 256   // per-row nnz capacity; E[nnz]=83, sd=9

// ---------------------------------------------------------------------------
// Kernel 1: H = X @ W^T + b ; s = H @ a_s ; r = H @ a_r   (unchanged)
// ---------------------------------------------------------------------------
__global__ __launch_bounds__(256) void linear_kernel(
    const float* __restrict__ X, const float* __restrict__ W,
    const float* __restrict__ b, const float* __restrict__ a_s,
    const float* __restrict__ a_r,
    float* __restrict__ H, float* __restrict__ sv, float* __restrict__ rv)
{
    __shared__ float Xs[128 * 36];
    __shared__ float Ws[64 * 132];

    const int tid = threadIdx.x;
    const int i0  = blockIdx.x * 32;

    for (int idx = tid; idx < 32 * 128; idx += 256) {
        const int row = idx >> 7, k = idx & 127;
        Xs[k * 36 + row] = X[(i0 + row) * D + k];
    }

    float acc[4][4] = {};
    const int ty = tid >> 5, tx = tid & 31;
    const int rbase = ty * 4, cbase = tx * 4;

    for (int kb = 0; kb < 2; ++kb) {
        __syncthreads();
        for (int idx = tid; idx < 64 * 128; idx += 256) {
            const int o = idx >> 6, kk = idx & 63;
            Ws[kk * 132 + o] = W[o * D + kb * 64 + kk];
        }
        __syncthreads();
        #pragma unroll
        for (int kk = 0; kk < 64; ++kk) {
            const float4 xv = *(const float4*)&Xs[(kb * 64 + kk) * 36 + rbase];
            const float4 wv = *(const float4*)&Ws[kk * 132 + cbase];
            const float xr[4] = {xv.x, xv.y, xv.z, xv.w};
            const float wc[4] = {wv.x, wv.y, wv.z, wv.w};
            #pragma unroll
            for (int r = 0; r < 4; ++r)
                #pragma unroll
                for (int c = 0; c < 4; ++c)
                    acc[r][c] += xr[r] * wc[c];
        }
    }

    const float4 bv  = *(const float4*)&b[cbase];
    const float4 asv = *(const float4*)&a_s[cbase];
    const float4 arv = *(const float4*)&a_r[cbase];
    #pragma unroll
    for (int r = 0; r < 4; ++r) {
        float4 h;
        h.x = acc[r][0] + bv.x;
        h.y = acc[r][1] + bv.y;
        h.z = acc[r][2] + bv.z;
        h.w = acc[r][3] + bv.w;
        *(float4*)&H[(size_t)(i0 + rbase + r) * D + cbase] = h;
        float ps = h.x * asv.x + h.y * asv.y + h.z * asv.z + h.w * asv.w;
        float pr = h.x * arv.x + h.y * arv.y + h.z * arv.z + h.w * arv.w;
        #pragma unroll
        for (int off = 16; off > 0; off >>= 1) {
            ps += __shfl_xor(ps, off);
            pr += __shfl_xor(pr, off);
        }
        if (tx == 0) {
            sv[i0 + rbase + r] = ps;
            rv[i0 + rbase + r] = pr;
        }
    }
}

// ---------------------------------------------------------------------------
// Kernel 2: fused scan + softmax + gather. ONE WAVE PER ROW.
// Phase 1: 8 iters x 4KB (4 float4/lane), ping-pong prefetch in NAMED
//          float4 registers with the iter loop FULLY UNROLLED (all indices
//          compile-time constant -> no scratch demotion; R4's buf[cb][q]
//          dynamic indexing spilled 256 MB to scratch).
//          One wave prefix-scan per 4KB; lanes scatter own cols to LDS.
//          List order != column order — softmax/sum are permutation-invariant.
// Phase 2: scores + shuffle softmax. Phase 3: coalesced H-gather.
// ---------------------------------------------------------------------------
__global__ __launch_bounds__(256, 6) void attn_fused(
    const float* __restrict__ A, const float* __restrict__ H,
    const float* __restrict__ sv, const float* __restrict__ rv,
    float* __restrict__ out)
{
    __shared__ float2 s_l[4][RCAP];   // .x = weight, .y = column index (bits)

    const int wave = threadIdx.x >> 6;
    const int lane = threadIdx.x & 63;
    const int i    = blockIdx.x * 4 + wave;

    const float4* __restrict__ Arow = (const float4*)(A + (size_t)i * N);

    // ---- phase 1: scan row, compact nonzero columns into LDS ----
    float4 c0 = Arow[0 * 64 + lane];
    float4 c1 = Arow[1 * 64 + lane];
    float4 c2 = Arow[2 * 64 + lane];
    float4 c3 = Arow[3 * 64 + lane];

    int cnt = 0;
    #pragma unroll
    for (int it = 0; it < 8; ++it) {
        float4 n0, n1, n2, n3;
        if (it < 7) {
            n0 = Arow[(it + 1) * 256 + 0 * 64 + lane];
            n1 = Arow[(it + 1) * 256 + 1 * 64 + lane];
            n2 = Arow[(it + 1) * 256 + 2 * 64 + lane];
            n3 = Arow[(it + 1) * 256 + 3 * 64 + lane];
        }
        // per-lane 16-bit nonzero mask (pure VALU)
        unsigned m = 0;
        m |= (c0.x != 0.0f ? 1u : 0u) << 0;
        m |= (c0.y != 0.0f ? 1u : 0u) << 1;
        m |= (c0.z != 0.0f ? 1u : 0u) << 2;
        m |= (c0.w != 0.0f ? 1u : 0u) << 3;
        m |= (c1.x != 0.0f ? 1u : 0u) << 4;
        m |= (c1.y != 0.0f ? 1u : 0u) << 5;
        m |= (c1.z != 0.0f ? 1u : 0u) << 6;
        m |= (c1.w != 0.0f ? 1u : 0u) << 7;
        m |= (c2.x != 0.0f ? 1u : 0u) << 8;
        m |= (c2.y != 0.0f ? 1u : 0u) << 9;
        m |= (c2.z != 0.0f ? 1u : 0u) << 10;
        m |= (c2.w != 0.0f ? 1u : 0u) << 11;
        m |= (c3.x != 0.0f ? 1u : 0u) << 12;
        m |= (c3.y != 0.0f ? 1u : 0u) << 13;
        m |= (c3.z != 0.0f ? 1u : 0u) << 14;
        m |= (c3.w != 0.0f ? 1u : 0u) << 15;

        const int c = __popc(m);
        // wave inclusive scan of c
        int scan = c;
        #pragma unroll
        for (int off = 1; off < 64; off <<= 1) {
            const int t = __shfl_up(scan, off);
            if (lane >= off) scan += t;
        }
        int base = cnt + scan - c;            // this lane's exclusive offset
        cnt += __shfl(scan, 63);              // wave-uniform total
        // scatter this lane's columns
        while (m) {
            const int k = __ffs(m) - 1;
            m &= m - 1;
            const int q = k >> 2, e = k & 3;
            if (base < RCAP)
                s_l[wave][base].y = __int_as_float(it * 1024 + q * 256 + lane * 4 + e);
            ++base;
        }
        c0 = n0; c1 = n1; c2 = n2; c3 = n3;
    }
    cnt = (cnt < RCAP) ? cnt : RCAP;

    // ---- phase 2: scores + softmax (<=4 entries per lane) ----
    const float si = sv[i];
    float zv[4];
    #pragma unroll
    for (int k = 0; k < 4; ++k) {
        const int p = lane + 64 * k;
        const bool act = (p < cnt);
        const int j = act ? __float_as_int(s_l[wave][p].y) : 0;
        float z = si + rv[j];
        z = (z > 0.0f) ? z : ALPHA * z;
        zv[k] = act ? z : -3.0e38f;
    }
    float lm = fmaxf(fmaxf(zv[0], zv[1]), fmaxf(zv[2], zv[3]));
    #pragma unroll
    for (int off = 32; off > 0; off >>= 1) lm = fmaxf(lm, __shfl_xor(lm, off));

    float sl = 0.0f;
    float wv4[4];
    #pragma unroll
    for (int k = 0; k < 4; ++k) {
        const int p = lane + 64 * k;
        const float w = (p < cnt) ? __expf(zv[k] - lm) : 0.0f;
        wv4[k] = w;
        sl += w;
    }
    #pragma unroll
    for (int off = 32; off > 0; off >>= 1) sl += __shfl_xor(sl, off);
    const float inv = 1.0f / sl;

    #pragma unroll
    for (int k = 0; k < 4; ++k) {
        const int p = lane + 64 * k;
        if (p < cnt) s_l[wave][p].x = wv4[k] * inv;
    }

    // ---- phase 3: weighted gather; each lane owns features 2*lane, 2*lane+1 ----
    float2 acc = make_float2(0.0f, 0.0f);
    const float* __restrict__ Hl = H + 2 * lane;
    #pragma unroll 4
    for (int p = 0; p < cnt; ++p) {
        const float2 wj = s_l[wave][p];               // one b64 broadcast read
        const int   j  = __float_as_int(wj.y);
        const float2 h = *(const float2*)&Hl[(size_t)j * D];
        acc.x += wj.x * h.x;
        acc.y += wj.x * h.y;
    }
    *(float2*)&out[(size_t)i * D + 2 * lane] = acc;
}

extern "C" void kernel_launch(void* const* d_in, const int* in_sizes, int n_in,
                              void* d_out, int out_size, void* d_ws, size_t ws_size,
                              hipStream_t stream) {
    const float* X   = (const float*)d_in[0];
    const float* A   = (const float*)d_in[1];
    const float* W   = (const float*)d_in[2];
    const float* b   = (const float*)d_in[3];
    const float* a_s = (const float*)d_in[4];
    const float* a_r = (const float*)d_in[5];
    float* out = (float*)d_out;

    float* H  = (float*)d_ws;               // N*D floats = 4 MB
    float* sv = H + (size_t)N * D;          // N floats
    float* rv = sv + N;                     // N floats

    linear_kernel<<<256, 256, 0, stream>>>(X, W, b, a_s, a_r, H, sv, rv);
    attn_fused<<<N / 4, 256, 0, stream>>>(A, H, sv, rv, out);
}